// Round 1
// baseline (97.232 us; speedup 1.0000x reference)
//
#include <hip/hip_runtime.h>

#define NUM_B 8
#define NUM_C 64
#define NUM_O 64
#define DIM_H 256
#define DIM_W 256
#define SEG   8
#define NSEG  (DIM_H / SEG)   // 32
#define TPB   512

__device__ __forceinline__ float uaf(unsigned u) { return __uint_as_float(u); }
__device__ __forceinline__ unsigned fau(float f) { return __float_as_uint(f); }
// round-to-nearest-even fp32 -> bf16 bits (data has no NaN/Inf)
__device__ __forceinline__ unsigned bf16r(float f) {
    unsigned u = fau(f);
    return (u + 0x7fffu + ((u >> 16) & 1u)) >> 16;
}

__global__ __launch_bounds__(TPB, 2)
void cpd_fused(const float* __restrict__ x, const float* __restrict__ w1,
               const float* __restrict__ wh, const float* __restrict__ wv,
               const float* __restrict__ bias, float* __restrict__ out)
{
    // LDS: 32 KiB x-row (bf16x2) + 16 KiB w1^T + small weights = ~50 KiB
    __shared__ unsigned xs[NUM_C][DIM_W / 2];   // xs[c][w/2] packed bf16 pair
    __shared__ float    w1t[NUM_C][NUM_O];      // w1t[c][o] = w1[o][c]
    __shared__ float    whs[NUM_O][4];
    __shared__ float    wvs[NUM_O][4];
    __shared__ float    bs[NUM_O];

    const int tid  = threadIdx.x;
    const int lane = tid & 63;
    const int wave = tid >> 6;          // [0,8): owns 8 out-channels
    const int bx   = blockIdx.x;        // [0,256)
    const int b    = bx >> 5;
    const int h0   = (bx & 31) * SEG;
    const int w4   = lane * 4;          // 4 consecutive w per lane

    // ---- stage weights into LDS ----
    for (int idx = tid; idx < NUM_C * NUM_O; idx += TPB) {
        int c = idx >> 6, o = idx & 63;
        w1t[c][o] = w1[o * NUM_C + c];
    }
    if (tid < NUM_O) {
        whs[tid][0] = wh[tid * 3 + 0];
        whs[tid][1] = wh[tid * 3 + 1];
        whs[tid][2] = wh[tid * 3 + 2];
        wvs[tid][0] = wv[tid * 3 + 0];
        wvs[tid][1] = wv[tid * 3 + 1];
        wvs[tid][2] = wv[tid * 3 + 2];
        bs[tid]     = bias[tid];
    }

    const int oc0 = wave * 8;   // this wave's out-channel base
    const int cb  = wave * 8;   // this wave's staged in-channel rows

    const float* xsrc = x + ((size_t)(b * NUM_C + cb) * DIM_H) * DIM_W + w4;

    float4 xr[8];   // next-row staging registers (8 c-rows x 4 floats)

    // prologue: issue loads for row h0-1 (if it exists)
    if (h0 - 1 >= 0) {
        const size_t ro = (size_t)(h0 - 1) * DIM_W;
        #pragma unroll
        for (int i = 0; i < 8; ++i)
            xr[i] = *(const float4*)(xsrc + (size_t)i * DIM_H * DIM_W + ro);
    }

    float zP[8][4], zPP[8][4];
    #pragma unroll
    for (int k = 0; k < 8; ++k)
        #pragma unroll
        for (int j = 0; j < 4; ++j) { zP[k][j] = 0.f; zPP[k][j] = 0.f; }

    __syncthreads();   // weights staged (full sync; also covers prologue)

    for (int hh = -1; hh <= SEG; ++hh) {
        const int  h  = h0 + hh;
        const bool hv = (h >= 0) && (h < DIM_H);

        __builtin_amdgcn_s_barrier();   // xs free (prev row's reads all consumed)

        if (hv) {
            // pack previous loads (compiler inserts vmcnt waits on xr use)
            #pragma unroll
            for (int i = 0; i < 8; ++i) {
                unsigned lo = bf16r(xr[i].x) | (bf16r(xr[i].y) << 16);
                unsigned hi = bf16r(xr[i].z) | (bf16r(xr[i].w) << 16);
                *(uint2*)&xs[cb + i][lane * 2] = make_uint2(lo, hi);
            }
        }
        // issue next row's loads; they stay in flight across the raw barrier
        if (hh < SEG && (h + 1) < DIM_H) {
            const size_t ro = (size_t)(h + 1) * DIM_W;
            #pragma unroll
            for (int i = 0; i < 8; ++i)
                xr[i] = *(const float4*)(xsrc + (size_t)i * DIM_H * DIM_W + ro);
        }

        asm volatile("s_waitcnt lgkmcnt(0)" ::: "memory");  // LDS writes visible
        __builtin_amdgcn_s_barrier();   // xs ready (vmcnt NOT drained)

        float zc[8][4];
        if (hv) {
            // ---- 1x1 projection: y[8 oc][4 w] ----
            float y[8][4];
            #pragma unroll
            for (int k = 0; k < 8; ++k)
                #pragma unroll
                for (int j = 0; j < 4; ++j) y[k][j] = 0.f;

            #pragma unroll 4
            for (int c = 0; c < NUM_C; ++c) {
                const uint2 u  = *(const uint2*)&xs[c][lane * 2];
                const float x0 = uaf(u.x << 16);
                const float x1 = uaf(u.x & 0xffff0000u);
                const float x2 = uaf(u.y << 16);
                const float x3 = uaf(u.y & 0xffff0000u);
                const float4 wa = *(const float4*)&w1t[c][oc0];
                const float4 wb = *(const float4*)&w1t[c][oc0 + 4];
                const float wk[8] = {wa.x, wa.y, wa.z, wa.w, wb.x, wb.y, wb.z, wb.w};
                #pragma unroll
                for (int k = 0; k < 8; ++k) {
                    y[k][0] = fmaf(wk[k], x0, y[k][0]);
                    y[k][1] = fmaf(wk[k], x1, y[k][1]);
                    y[k][2] = fmaf(wk[k], x2, y[k][2]);
                    y[k][3] = fmaf(wk[k], x3, y[k][3]);
                }
            }

            // ---- horizontal 1x3 via wave shuffles (full W per wave) ----
            #pragma unroll
            for (int k = 0; k < 8; ++k) {
                float l = __shfl_up(y[k][3], 1u);
                float r = __shfl_down(y[k][0], 1u);
                if (lane == 0)  l = 0.f;
                if (lane == 63) r = 0.f;
                const float a0 = whs[oc0 + k][0];
                const float a1 = whs[oc0 + k][1];
                const float a2 = whs[oc0 + k][2];
                zc[k][0] = a0 * l       + a1 * y[k][0] + a2 * y[k][1];
                zc[k][1] = a0 * y[k][0] + a1 * y[k][1] + a2 * y[k][2];
                zc[k][2] = a0 * y[k][1] + a1 * y[k][2] + a2 * y[k][3];
                zc[k][3] = a0 * y[k][2] + a1 * y[k][3] + a2 * r;
            }
        } else {
            #pragma unroll
            for (int k = 0; k < 8; ++k)
                #pragma unroll
                for (int j = 0; j < 4; ++j) zc[k][j] = 0.f;
        }

        // ---- vertical 3x1 + bias: out row g = h-1 complete ----
        if (hh >= 1) {
            const int g = h - 1;
            #pragma unroll
            for (int k = 0; k < 8; ++k) {
                const float v0 = wvs[oc0 + k][0];
                const float v1 = wvs[oc0 + k][1];
                const float v2 = wvs[oc0 + k][2];
                const float bk = bs[oc0 + k];
                float4 o;
                o.x = bk + v0 * zPP[k][0] + v1 * zP[k][0] + v2 * zc[k][0];
                o.y = bk + v0 * zPP[k][1] + v1 * zP[k][1] + v2 * zc[k][1];
                o.z = bk + v0 * zPP[k][2] + v1 * zP[k][2] + v2 * zc[k][2];
                o.w = bk + v0 * zPP[k][3] + v1 * zP[k][3] + v2 * zc[k][3];
                *(float4*)(out + (((size_t)(b * NUM_O + oc0 + k) * DIM_H + g) * DIM_W + w4)) = o;
            }
        }

        // rotate z history
        #pragma unroll
        for (int k = 0; k < 8; ++k)
            #pragma unroll
            for (int j = 0; j < 4; ++j) { zPP[k][j] = zP[k][j]; zP[k][j] = zc[k][j]; }
    }
}

extern "C" void kernel_launch(void* const* d_in, const int* in_sizes, int n_in,
                              void* d_out, int out_size, void* d_ws, size_t ws_size,
                              hipStream_t stream) {
    const float* x    = (const float*)d_in[0];
    const float* w1   = (const float*)d_in[1];
    const float* wh   = (const float*)d_in[2];
    const float* wv   = (const float*)d_in[3];
    const float* bias = (const float*)d_in[4];
    float* outp = (float*)d_out;
    cpd_fused<<<dim3(NUM_B * NSEG), dim3(TPB), 0, stream>>>(x, w1, wh, wv, bias, outp);
}

// Round 2
// 59.558 us; speedup vs baseline: 1.6326x; 1.6326x over previous
//
#include <hip/hip_runtime.h>

#define NUM_B 8
#define NUM_C 64
#define NUM_O 64
#define DIM_H 256
#define DIM_W 256
#define SEG   8
#define TPB   512
#define XSS   72          // xs row stride in bf16 elems (64 + 8 pad): 144 B = 36 dwords, gcd-free vs 32 banks

typedef __attribute__((ext_vector_type(8))) short bf16x8;
typedef __attribute__((ext_vector_type(4))) float f32x4;

__device__ __forceinline__ unsigned bf16r(float f) {   // RTNE fp32 -> bf16 bits
    unsigned u = __float_as_uint(f);
    return (u + 0x7fffu + ((u >> 16) & 1u)) >> 16;
}
__device__ __forceinline__ unsigned cvt_pk_bf16(float lo, float hi) {
    unsigned r;
    asm("v_cvt_pk_bf16_f32 %0, %1, %2" : "=v"(r) : "v"(lo), "v"(hi));
    return r;
}

__global__ __launch_bounds__(TPB, 2)
void cpd_mfma(const float* __restrict__ x, const float* __restrict__ w1,
              const float* __restrict__ wh, const float* __restrict__ wv,
              const float* __restrict__ bias, float* __restrict__ out)
{
    // one x-row, transposed: xs[w+1][c] bf16; rows 0 and DIM_W+1 are zero pad for the w-shifts
    __shared__ unsigned short xs[DIM_W + 2][XSS];

    const int tid  = threadIdx.x;
    const int lane = tid & 63;
    const int wave = tid >> 6;
    const int l15  = lane & 15;
    const int lhi  = lane >> 4;
    const int bx   = blockIdx.x;
    const int b    = bx >> 5;
    const int h0   = (bx & 31) * SEG;

    const int ot  = wave & 3;    // o-tile [0,4): o = ot*16 ..
    const int wh2 = wave >> 2;   // w-half [0,2): w = wh2*128 ..

    // ---- A fragments (held in regs all kernel): A_s[o][c] = wh[o][s] * w1[o][c] ----
    // lane slot (l,i): m = l&15, k = (l>>4)*8 + i  (same assumed mapping used for B)
    bf16x8 afrag[3][2];
    {
        const int o = ot * 16 + l15;
        const float a0 = wh[o*3+0], a1 = wh[o*3+1], a2 = wh[o*3+2];
        #pragma unroll
        for (int kb = 0; kb < 2; ++kb) {
            const float* wr = w1 + o * NUM_C + kb * 32 + lhi * 8;
            const float4 wa = *(const float4*)wr;
            const float4 wb = *(const float4*)(wr + 4);
            const float w8[8] = {wa.x,wa.y,wa.z,wa.w,wb.x,wb.y,wb.z,wb.w};
            #pragma unroll
            for (int i = 0; i < 8; ++i) {
                afrag[0][kb][i] = (short)bf16r(a0 * w8[i]);
                afrag[1][kb][i] = (short)bf16r(a1 * w8[i]);
                afrag[2][kb][i] = (short)bf16r(a2 * w8[i]);
            }
        }
    }
    // vertical-conv coefficients + bias, per C/D reg r: o = ot*16 + (lane>>4)*4 + r
    float v0c[4], v1c[4], v2c[4], bc[4];
    #pragma unroll
    for (int r = 0; r < 4; ++r) {
        const int o = ot * 16 + lhi * 4 + r;
        v0c[r] = wv[o*3+0]; v1c[r] = wv[o*3+1]; v2c[r] = wv[o*3+2];
        bc[r]  = bias[o];
    }

    if (tid < XSS) { xs[0][tid] = 0; xs[DIM_W + 1][tid] = 0; }

    // staging: thread owns w = tid&255, c-chunk ch; per row: 32 strided-coalesced dword loads
    const int sw = tid & 255;
    const int ch = tid >> 8;
    const float* xb = x + (size_t)b * NUM_C * DIM_H * DIM_W + sw;

    float xr[32];
    if (h0 > 0) {
        #pragma unroll
        for (int p = 0; p < 8; ++p) {
            const int c0 = p * 8 + ch * 4;
            #pragma unroll
            for (int j = 0; j < 4; ++j)
                xr[p*4+j] = xb[(size_t)(c0+j) * (DIM_H*DIM_W) + (size_t)(h0-1) * DIM_W];
        }
    }

    f32x4 zP[8], zPP[8];
    #pragma unroll
    for (int t = 0; t < 8; ++t) {
        zP[t]  = (f32x4){0.f,0.f,0.f,0.f};
        zPP[t] = (f32x4){0.f,0.f,0.f,0.f};
    }

    for (int hh = -1; hh <= SEG; ++hh) {
        const int h = h0 + hh;
        const bool hv = (h >= 0) && (h < DIM_H);

        __builtin_amdgcn_s_barrier();          // xs free (prev row fully consumed)
        __builtin_amdgcn_sched_barrier(0);

        if (hv) {
            // pack previously-loaded row into LDS (compiler inserts vmcnt waits on xr use)
            #pragma unroll
            for (int p = 0; p < 8; ++p) {
                const unsigned lo = cvt_pk_bf16(xr[p*4+0], xr[p*4+1]);
                const unsigned hi = cvt_pk_bf16(xr[p*4+2], xr[p*4+3]);
                *(uint2*)&xs[sw + 1][p * 8 + ch * 4] = make_uint2(lo, hi);
            }
        }
        // issue next row's loads; they stay in flight across the raw barriers
        if (hh < SEG && h + 1 < DIM_H) {
            #pragma unroll
            for (int p = 0; p < 8; ++p) {
                const int c0 = p * 8 + ch * 4;
                #pragma unroll
                for (int j = 0; j < 4; ++j)
                    xr[p*4+j] = xb[(size_t)(c0+j) * (DIM_H*DIM_W) + (size_t)(h+1) * DIM_W];
            }
        }

        asm volatile("s_waitcnt lgkmcnt(0)" ::: "memory");   // LDS writes visible
        __builtin_amdgcn_s_barrier();          // xs ready (vmcnt NOT drained)
        __builtin_amdgcn_sched_barrier(0);

        f32x4 acc[8];
        #pragma unroll
        for (int t = 0; t < 8; ++t) acc[t] = (f32x4){0.f,0.f,0.f,0.f};

        if (hv) {
            // z-row = sum_s A_s . X(w + s - 1): horizontal conv folded into 3 shifted GEMMs
            const int cb = lhi * 8;
            #pragma unroll
            for (int t = 0; t < 8; ++t) {
                const unsigned short* rp0 = &xs[wh2 * 128 + t * 16 + l15][cb];
                #pragma unroll
                for (int s = 0; s < 3; ++s) {
                    const unsigned short* rp = rp0 + s * XSS;
                    const bf16x8 b0 = *(const bf16x8*)rp;          // c 0..31 slice
                    const bf16x8 b1 = *(const bf16x8*)(rp + 32);   // c 32..63 slice
                    acc[t] = __builtin_amdgcn_mfma_f32_16x16x32_bf16(afrag[s][0], b0, acc[t], 0, 0, 0);
                    acc[t] = __builtin_amdgcn_mfma_f32_16x16x32_bf16(afrag[s][1], b1, acc[t], 0, 0, 0);
                }
            }
        }

        // vertical 3x1 + bias: out row g = h-1 complete
        if (hh >= 1) {
            float* ob = out + (size_t)b * NUM_O * DIM_H * DIM_W + (size_t)(h - 1) * DIM_W;
            #pragma unroll
            for (int t = 0; t < 8; ++t) {
                const int w = wh2 * 128 + t * 16 + l15;
                #pragma unroll
                for (int r = 0; r < 4; ++r) {
                    const int o = ot * 16 + lhi * 4 + r;
                    ob[(size_t)o * (DIM_H * DIM_W) + w] =
                        bc[r] + v0c[r]*zPP[t][r] + v1c[r]*zP[t][r] + v2c[r]*acc[t][r];
                }
            }
        }

        #pragma unroll
        for (int t = 0; t < 8; ++t) { zPP[t] = zP[t]; zP[t] = acc[t]; }
    }
}

extern "C" void kernel_launch(void* const* d_in, const int* in_sizes, int n_in,
                              void* d_out, int out_size, void* d_ws, size_t ws_size,
                              hipStream_t stream) {
    const float* x    = (const float*)d_in[0];
    const float* w1   = (const float*)d_in[1];
    const float* wh   = (const float*)d_in[2];
    const float* wv   = (const float*)d_in[3];
    const float* bias = (const float*)d_in[4];
    float* outp = (float*)d_out;
    cpd_mfma<<<dim3(NUM_B * (DIM_H / SEG)), dim3(TPB), 0, stream>>>(x, w1, wh, wv, bias, outp);
}